// Round 15
// baseline (4710.963 us; speedup 1.0000x reference)
//
#include <hip/hip_runtime.h>
#include <hip/hip_fp16.h>

#define TSTEPS 512
#define NB 128
#define NI 512
#define HID 1024
#define NWGS 256

typedef _Float16 __attribute__((ext_vector_type(8))) half8;
typedef float __attribute__((ext_vector_type(16))) floatx16;
typedef float __attribute__((ext_vector_type(4))) float4v;
typedef unsigned __attribute__((ext_vector_type(4))) uint4v;

// ---------------- ws layout ----------------
// wpack : [hs=128][kt=96][lane=64][e=8] fp16   = 12,582,912 B  (B-frag packed)
// hbuf0 : [mh=2][hs=128][tid=256] u32          =    262,144 B  (h handoff, ping)
// hbuf1 : same                                                 (pong)
// bar   : SHARDED epoch slots: slot(wg) = bar[(wg>>2)*32 + (wg&3)], 2048 u32
// xpk   : [t=512][mt=4][xt=32][lane=64][e=8] fp16 = 67,108,864 B (A-frag packed x)
#define WPACK_OFF 0
#define HB0_OFF   12582912
#define HB1_OFF   12845056
#define BAR_OFF   13107200
#define XPK_OFF   13115392
#define XPK_NEED  ((size_t)XPK_OFF + (size_t)67108864)

// LDS: wlds 98304 B | pbuf [kq*2+mt][n=32][36f] 36864 B | hshare [64][11f] 2816 B
#define LDS_PBUF  98304
#define LDS_HSH   135168
#define LDS_TOTAL 137984

__device__ __forceinline__ short f2h(float f) {
  _Float16 h = (_Float16)f;
  return *reinterpret_cast<short*>(&h);
}
__device__ __forceinline__ unsigned pack2(float a, float b) {
  return ((unsigned)(unsigned short)f2h(b) << 16) | (unsigned)(unsigned short)f2h(a);
}

__device__ __forceinline__ half8 pack8(float4v a, float4v b) {
  half8 r;
  r[0] = (_Float16)a[0]; r[1] = (_Float16)a[1]; r[2] = (_Float16)a[2]; r[3] = (_Float16)a[3];
  r[4] = (_Float16)b[0]; r[5] = (_Float16)b[1]; r[6] = (_Float16)b[2]; r[7] = (_Float16)b[3];
  return r;
}

__device__ __forceinline__ float sigf(float x) { return 1.f / (1.f + __expf(-x)); }

// Coherence-point (bypass L1+L2) accessors. sc0 sc1 = system-scope: loads read
// fresh from the coherence point (NO buffer_inv), stores write through to it.
__device__ __forceinline__ uint4v cp_load4(const unsigned* p) {
  uint4v v;
  asm volatile("global_load_dwordx4 %0, %1, off sc0 sc1" : "=v"(v) : "v"(p) : "memory");
  asm volatile("s_waitcnt vmcnt(0)" ::: "memory");
  return v;
}
__device__ __forceinline__ void cp_store(unsigned* p, unsigned v) {
  asm volatile("global_store_dword %0, %1, off sc0 sc1" :: "v"(p), "v"(v) : "memory");
}
__device__ __forceinline__ void cp_store4(unsigned* p, uint4v v) {
  asm volatile("global_store_dwordx4 %0, %1, off sc0 sc1" :: "v"(p), "v"(v) : "memory");
}

// Pack 4 gate weight matrices (fp32, each [1024][1536]) into fp16 B-fragments.
__global__ void pack_w(const float* __restrict__ Wf, const float* __restrict__ Wi,
                       const float* __restrict__ Wc, const float* __restrict__ Wo,
                       _Float16* __restrict__ wpack) {
  int idx = blockIdx.x * 256 + threadIdx.x;      // one 8-elem lane-chunk each
  if (idx >= 128 * 96 * 64) return;
  int lane = idx & 63;
  int rest = idx >> 6;
  int kt = rest % 96;
  int hs = rest / 96;
  int n = lane & 31, q = lane >> 5;
  int j = n >> 2, g = n & 3;
  int row = hs * 8 + j;
  int k = kt * 16 + q * 8;
  const float* W = (g == 0) ? Wf : (g == 1) ? Wi : (g == 2) ? Wc : Wo;
  const float* src = W + (size_t)row * 1536 + k;
  _Float16* dst = wpack + (size_t)idx * 8;
  #pragma unroll
  for (int e = 0; e < 8; e++) dst[e] = (_Float16)src[e];
}

// Pack x (fp32) into A-frag fp16: xpk[((t*4+mt)*32+xt)*64+lane][e],
// element = x[t][mt*32 + (lane&31)][xt*16 + (lane>>5)*8 + e]. Same cvt as pack8.
__global__ void pack_x(const float* __restrict__ x, _Float16* __restrict__ xpk) {
  int idx = blockIdx.x * 256 + threadIdx.x;      // [t][mt][xt][lane]
  int lane = idx & 63;
  int rest = idx >> 6;
  int xt = rest & 31;
  rest >>= 5;
  int mt = rest & 3;
  int t = rest >> 2;
  int n32 = lane & 31, q = lane >> 5;
  const float* src = x + ((size_t)t * NB + mt * 32 + n32) * NI + xt * 16 + q * 8;
  _Float16* dst = xpk + (size_t)idx * 8;
  #pragma unroll
  for (int e = 0; e < 8; e++) dst[e] = (_Float16)src[e];
}

__global__ void zero_h(unsigned* __restrict__ hb0, unsigned* __restrict__ bar) {
  int i = blockIdx.x * 256 + threadIdx.x;
  // system-scope stores: initial state must be visible to CP-bypass reads
  if (i < 65536)
    __hip_atomic_store(&hb0[i], 0u, __ATOMIC_RELAXED, __HIP_MEMORY_SCOPE_SYSTEM);
  if (i < 2048)
    __hip_atomic_store(&bar[i], 0u, __ATOMIC_RELAXED, __HIP_MEMORY_SCOPE_SYSTEM);
}

__global__ void __launch_bounds__(256, 1)
lstm_main(const float* __restrict__ x,
          const float* __restrict__ bfv, const float* __restrict__ biv,
          const float* __restrict__ bcv, const float* __restrict__ bov,
          const _Float16* __restrict__ wpack, const _Float16* __restrict__ xpk,
          int xp_en,
          _Float16* __restrict__ hb0, _Float16* __restrict__ hb1,
          unsigned* __restrict__ bar, float* __restrict__ out) {
  extern __shared__ char lds[];
  short* wlds = (short*)lds;                      // [96][64][8] fp16 bits
  float* pbuf = (float*)(lds + LDS_PBUF);         // [(kq*2+mt)*32+n][36]
  float* hshare = (float*)(lds + LDS_HSH);        // [64][11] (stride 11: bank-clean)

  const int tid = threadIdx.x;
  const int lane = tid & 63;
  const int wv = tid >> 6;                        // kq 0..3
  const int hs = blockIdx.x & 127;                // h-slice (8 cols)
  const int mh = blockIdx.x >> 7;                 // batch half

  // ---- load this WG's weight slice into LDS (persistent) ----
  {
    const uint4* src = (const uint4*)wpack + (size_t)hs * 6144;   // 96*64*16B
    uint4* dst = (uint4*)wlds;
    #pragma unroll
    for (int i = 0; i < 24; i++) dst[i * 256 + tid] = src[i * 256 + tid];
  }

  // ---- reducer thread state (tid < 128): 4 cells (m4 block) x 1 h-col ----
  const int rj = tid & 7;
  const int rm4 = tid >> 3;                       // 0..15
  float rbias[4] = {0.f, 0.f, 0.f, 0.f};
  float cstate[4] = {0.f, 0.f, 0.f, 0.f};
  if (tid < 128) {
    int hg = hs * 8 + rj;
    rbias[0] = bfv[hg]; rbias[1] = biv[hg]; rbias[2] = bcv[hg]; rbias[3] = bov[hg];
  }

  const int n32 = lane & 31;
  const int q = lane >> 5;

  // Sharded slot address for THIS WG: 4 slots per 128B line.
  unsigned* myslot = bar + ((blockIdx.x >> 2) * 32 + (blockIdx.x & 3));
  // This WAVE's 32 producers (WGs mh*128 + wv*32 .. +31) occupy 8 sharded lines;
  // lanes 0..7 poll one line each (dwordx4 covers its 4 slots).
  const unsigned* pline = bar + (((mh * 128 + wv * 32) >> 2) + (lane & 7)) * 32;

  __syncthreads();

  for (int t = 0; t < TSTEPS; t++) {
    const _Float16* hrd = (t & 1) ? hb1 : hb0;
    _Float16* hwr = (t & 1) ? hb0 : hb1;

    floatx16 acc0, acc1;
    #pragma unroll
    for (int i = 0; i < 16; i++) { acc0[i] = 0.f; acc1[i] = 0.f; }

    // ---- x-part (kt 64..95): independent of h_{t-1}; overlaps this wave's wait ----
    if (xp_en) {
      // pre-packed fp16 A-frags: pure 16B cached loads, no cvt on critical path
      const _Float16* xp = xpk + (((size_t)t * 4 + mh * 2) * 32) * 64 * 8;
      #pragma unroll
      for (int kk = 0; kk < 8; kk++) {
        int xt = wv * 8 + kk;
        half8 bfrag = *(const half8*)(wlds + ((64 + xt) * 64 + lane) * 8);
        half8 a0 = *(const half8*)(xp + ((size_t)(0 * 32 + xt) * 64 + lane) * 8);
        half8 a1 = *(const half8*)(xp + ((size_t)(1 * 32 + xt) * 64 + lane) * 8);
        acc0 = __builtin_amdgcn_mfma_f32_32x32x16_f16(a0, bfrag, acc0, 0, 0, 0);
        acc1 = __builtin_amdgcn_mfma_f32_32x32x16_f16(a1, bfrag, acc1, 0, 0, 0);
      }
    } else {
      const float* xbase = x + (size_t)t * NB * NI;
      const int r0 = (mh * 2 + 0) * 32 + n32;
      #pragma unroll
      for (int kk = 0; kk < 8; kk++) {
        int xt = wv * 8 + kk;
        half8 bfrag = *(const half8*)(wlds + ((64 + xt) * 64 + lane) * 8);
        const float* xs = xbase + xt * 16 + q * 8;
        float4v xa0 = *(const float4v*)(xs + (size_t)r0 * NI);
        float4v xb0 = *(const float4v*)(xs + (size_t)r0 * NI + 4);
        float4v xa1 = *(const float4v*)(xs + (size_t)(r0 + 32) * NI);
        float4v xb1 = *(const float4v*)(xs + (size_t)(r0 + 32) * NI + 4);
        acc0 = __builtin_amdgcn_mfma_f32_32x32x16_f16(pack8(xa0, xb0), bfrag, acc0, 0, 0, 0);
        acc1 = __builtin_amdgcn_mfma_f32_32x32x16_f16(pack8(xa1, xb1), bfrag, acc1, 0, 0, 0);
      }
    }

    // ---- PER-WAVE dataflow wait: only this wave's 32 producers (8 lines).
    //      No acquire-inv anywhere; no WG-wide gate. The poll's vmcnt(0) drains
    //      the wave's counter, keeping the counted h-load waits exact.
    if (t > 0) {
      const unsigned need = (unsigned)t;
      for (;;) {
        int ok = 1;
        if (lane < 8) {
          uint4v v = cp_load4(pline);
          ok = (v[0] >= need) & (v[1] >= need) & (v[2] >= need) & (v[3] >= need);
        }
        if (__all(ok)) break;
        __builtin_amdgcn_s_sleep(1);
      }
    }

    // ---- h-part (kt 0..63): 16 tiles per wave, WG-contiguous block layout,
    //      read DIRECTLY from the coherence point. dwordx4 bypass loads (16B/lane:
    //      a0 at base, a1 at base+512 via imm offset). Hand-pipelined: issue 16
    //      loads, then counted vmcnt + sched_barrier per tile (rule #18).
    {
      const char* hp = (const char*)hrd + ((size_t)mh << 17);   // my half: 128 KB
      #pragma unroll
      for (int ph = 0; ph < 2; ph++) {
        uint4v wa[8], wb[8];
        #pragma unroll
        for (int kk = 0; kk < 8; kk++) {
          int ht = wv * 16 + ph * 8 + kk;
          const char* base = hp + (((ht * 2 + q) << 10) | (n32 << 4));
          asm volatile("global_load_dwordx4 %0, %1, off sc0 sc1"
                       : "=v"(wa[kk]) : "v"(base));
          asm volatile("global_load_dwordx4 %0, %1, off offset:512 sc0 sc1"
                       : "=v"(wb[kk]) : "v"(base));
        }
        #pragma unroll
        for (int kk = 0; kk < 8; kk++) {
          int ht = wv * 16 + ph * 8 + kk;
          half8 bfrag = *(const half8*)(wlds + (ht * 64 + lane) * 8);
          asm volatile("s_waitcnt vmcnt(%0)" :: "i"(14 - 2 * kk) : "memory");
          __builtin_amdgcn_sched_barrier(0);
          union { uint4v u; half8 h; } ua, ub;
          ua.u = wa[kk]; ub.u = wb[kk];
          acc0 = __builtin_amdgcn_mfma_f32_32x32x16_f16(ua.h, bfrag, acc0, 0, 0, 0);
          acc1 = __builtin_amdgcn_mfma_f32_32x32x16_f16(ub.h, bfrag, acc1, 0, 0, 0);
        }
      }
    }

    // ---- partials to LDS: D[m][n], m = (r&3) + 8*(r>>2) + 4*q, n = lane&31 ----
    {
      float* b0 = pbuf + ((wv * 2 + 0) * 32 + n32) * 36 + q * 4;
      float* b1 = pbuf + ((wv * 2 + 1) * 32 + n32) * 36 + q * 4;
      #pragma unroll
      for (int rg = 0; rg < 4; rg++) {
        float4v v0 = {acc0[rg * 4 + 0], acc0[rg * 4 + 1], acc0[rg * 4 + 2], acc0[rg * 4 + 3]};
        float4v v1 = {acc1[rg * 4 + 0], acc1[rg * 4 + 1], acc1[rg * 4 + 2], acc1[rg * 4 + 3]};
        *(float4v*)(b0 + rg * 8) = v0;
        *(float4v*)(b1 + rg * 8) = v1;
      }
    }
    __syncthreads();                              // re-converge all waves

    // ---- reduce over kq, gate math, c update (tid < 128) ----
    if (tid < 128) {
      const int mt = rm4 >> 3;
      const int mb = (rm4 & 7) * 4;
      float4v s[4];
      #pragma unroll
      for (int g = 0; g < 4; g++) {
        const float* p = pbuf + (mt * 32 + rj * 4 + g) * 36 + mb;
        float4v a = *(const float4v*)(p);
        a += *(const float4v*)(p + 1 * 2 * 32 * 36);
        a += *(const float4v*)(p + 2 * 2 * 32 * 36);
        a += *(const float4v*)(p + 3 * 2 * 32 * 36);
        s[g] = a;
      }
      #pragma unroll
      for (int r = 0; r < 4; r++) {
        float fg = sigf(s[0][r] + rbias[0]);
        float ig = sigf(s[1][r] + rbias[1]);
        float cg = tanhf(s[2][r] + rbias[2]);
        float og = sigf(s[3][r] + rbias[3]);
        float cn = fg * cstate[r] + ig * cg;
        cstate[r] = cn;
        hshare[(rm4 * 4 + r) * 11 + rj] = og * tanhf(cn);
      }
    }
    __syncthreads();                              // hshare ready (orders pbuf too)

    // ---- WAVE-0-ONLY h publish: 64 lanes x one 16B write-through each (4x fewer
    //      CP acks than 256 scalar stores), then the wave's own vmcnt(0) + slot
    //      store. No extra __syncthreads: vmcnt is per-wave, and hshare/pbuf
    //      reuse at t+1 is ordered by the next pbuf __syncthreads (needs wave 0).
    if (t < TSTEPS - 1 && tid < 64) {
      float v0 = hshare[tid * 11 + 0], v1 = hshare[tid * 11 + 1];
      float v2 = hshare[tid * 11 + 2], v3 = hshare[tid * 11 + 3];
      float v4 = hshare[tid * 11 + 4], v5 = hshare[tid * 11 + 5];
      float v6 = hshare[tid * 11 + 6], v7 = hshare[tid * 11 + 7];
      uint4v u;
      u[0] = pack2(v0, v1); u[1] = pack2(v2, v3);
      u[2] = pack2(v4, v5); u[3] = pack2(v6, v7);
      // block byte offset = ml*16 (ml = tid): matches consumer layout exactly
      unsigned* dst = (unsigned*)((char*)hwr + (((mh * 128 + hs) << 10))) + tid * 4;
      cp_store4(dst, u);
      asm volatile("s_waitcnt vmcnt(0)" ::: "memory");
      if (tid == 0) cp_store(myslot, (unsigned)(t + 1));
    }

    // ---- out (fp32, plain cached, all threads) — off the arrive path ----
    {
      const int ml = tid >> 2;
      const int j0 = (tid & 3) * 2;
      float h0 = hshare[ml * 11 + j0];
      float h1 = hshare[ml * 11 + j0 + 1];
      const int mg = mh * 64 + ml;
      const int hg = hs * 8 + j0;
      *(float2*)(out + ((size_t)t * NB + mg) * HID + hg) = make_float2(h0, h1);
    }
  }
}

extern "C" void kernel_launch(void* const* d_in, const int* in_sizes, int n_in,
                              void* d_out, int out_size, void* d_ws, size_t ws_size,
                              hipStream_t stream) {
  const float* x   = (const float*)d_in[0];
  const float* Wf  = (const float*)d_in[1];
  const float* bf_ = (const float*)d_in[2];
  const float* Wi  = (const float*)d_in[3];
  const float* bi_ = (const float*)d_in[4];
  const float* Wc  = (const float*)d_in[5];
  const float* bc_ = (const float*)d_in[6];
  const float* Wo  = (const float*)d_in[7];
  const float* bo_ = (const float*)d_in[8];
  float* out = (float*)d_out;

  char* ws = (char*)d_ws;
  _Float16* wpack = (_Float16*)(ws + WPACK_OFF);
  _Float16* hb0   = (_Float16*)(ws + HB0_OFF);
  _Float16* hb1   = (_Float16*)(ws + HB1_OFF);
  unsigned* bar   = (unsigned*)(ws + BAR_OFF);
  _Float16* xpk   = (_Float16*)(ws + XPK_OFF);
  int xp_en = (ws_size >= XPK_NEED) ? 1 : 0;

  pack_w<<<3072, 256, 0, stream>>>(Wf, Wi, Wc, Wo, wpack);
  if (xp_en) pack_x<<<16384, 256, 0, stream>>>(x, xpk);
  zero_h<<<257, 256, 0, stream>>>((unsigned*)hb0, bar);

  hipFuncSetAttribute(reinterpret_cast<const void*>(lstm_main),
                      hipFuncAttributeMaxDynamicSharedMemorySize, LDS_TOTAL);

  void* args[] = {(void*)&x, (void*)&bf_, (void*)&bi_, (void*)&bc_, (void*)&bo_,
                  (void*)&wpack, (void*)&xpk, (void*)&xp_en,
                  (void*)&hb0, (void*)&hb1, (void*)&bar, (void*)&out};
  hipLaunchCooperativeKernel(reinterpret_cast<void*>(lstm_main),
                             dim3(NWGS), dim3(256), args, LDS_TOTAL, stream);
}

// Round 16
// 4615.531 us; speedup vs baseline: 1.0207x; 1.0207x over previous
//
#include <hip/hip_runtime.h>
#include <hip/hip_fp16.h>

#define TSTEPS 512
#define NB 128
#define NI 512
#define HID 1024
#define NWGS 256

typedef _Float16 __attribute__((ext_vector_type(8))) half8;
typedef float __attribute__((ext_vector_type(16))) floatx16;
typedef float __attribute__((ext_vector_type(4))) float4v;
typedef unsigned __attribute__((ext_vector_type(4))) uint4v;

// ---------------- ws layout ----------------
// wpack : [hs=128][kt=96][lane=64][e=8] fp16   = 12,582,912 B  (B-frag packed)
// hbuf0 : [mh=2][hs=128][tid=256] u32          =    262,144 B  (h handoff, ping)
// hbuf1 : same                                                 (pong)
// bar   : SHARDED epoch slots: slot(wg) = bar[(wg>>2)*32 + (wg&3)], 2048 u32
// xpk   : [t=512][mt=4][xt=32][lane=64][e=8] fp16 = 67,108,864 B (A-frag packed x)
#define WPACK_OFF 0
#define HB0_OFF   12582912
#define HB1_OFF   12845056
#define BAR_OFF   13107200
#define XPK_OFF   13115392
#define XPK_NEED  ((size_t)XPK_OFF + (size_t)67108864)

// LDS: wlds 98304 B  |  pbuf [kq*2+mt][n=32][36f] 36864 B  |  hshare [64][10f] 2560 B
#define LDS_PBUF  98304
#define LDS_HSH   135168
#define LDS_TOTAL 137728

__device__ __forceinline__ short f2h(float f) {
  _Float16 h = (_Float16)f;
  return *reinterpret_cast<short*>(&h);
}

__device__ __forceinline__ half8 pack8(float4v a, float4v b) {
  half8 r;
  r[0] = (_Float16)a[0]; r[1] = (_Float16)a[1]; r[2] = (_Float16)a[2]; r[3] = (_Float16)a[3];
  r[4] = (_Float16)b[0]; r[5] = (_Float16)b[1]; r[6] = (_Float16)b[2]; r[7] = (_Float16)b[3];
  return r;
}

__device__ __forceinline__ float sigf(float x) { return 1.f / (1.f + __expf(-x)); }

// Coherence-point (bypass L1+L2) accessors. sc0 sc1 = system-scope: loads read
// fresh from the coherence point (NO buffer_inv), stores write through to it.
__device__ __forceinline__ uint4v cp_load4(const unsigned* p) {
  uint4v v;
  asm volatile("global_load_dwordx4 %0, %1, off sc0 sc1" : "=v"(v) : "v"(p) : "memory");
  asm volatile("s_waitcnt vmcnt(0)" ::: "memory");
  return v;
}
__device__ __forceinline__ void cp_store(unsigned* p, unsigned v) {
  asm volatile("global_store_dword %0, %1, off sc0 sc1" :: "v"(p), "v"(v) : "memory");
}

// Pack 4 gate weight matrices (fp32, each [1024][1536]) into fp16 B-fragments.
__global__ void pack_w(const float* __restrict__ Wf, const float* __restrict__ Wi,
                       const float* __restrict__ Wc, const float* __restrict__ Wo,
                       _Float16* __restrict__ wpack) {
  int idx = blockIdx.x * 256 + threadIdx.x;      // one 8-elem lane-chunk each
  if (idx >= 128 * 96 * 64) return;
  int lane = idx & 63;
  int rest = idx >> 6;
  int kt = rest % 96;
  int hs = rest / 96;
  int n = lane & 31, q = lane >> 5;
  int j = n >> 2, g = n & 3;
  int row = hs * 8 + j;
  int k = kt * 16 + q * 8;
  const float* W = (g == 0) ? Wf : (g == 1) ? Wi : (g == 2) ? Wc : Wo;
  const float* src = W + (size_t)row * 1536 + k;
  _Float16* dst = wpack + (size_t)idx * 8;
  #pragma unroll
  for (int e = 0; e < 8; e++) dst[e] = (_Float16)src[e];
}

// Pack x (fp32) into A-frag fp16: xpk[((t*4+mt)*32+xt)*64+lane][e],
// element = x[t][mt*32 + (lane&31)][xt*16 + (lane>>5)*8 + e]. Same cvt as pack8.
__global__ void pack_x(const float* __restrict__ x, _Float16* __restrict__ xpk) {
  int idx = blockIdx.x * 256 + threadIdx.x;      // [t][mt][xt][lane]
  int lane = idx & 63;
  int rest = idx >> 6;
  int xt = rest & 31;
  rest >>= 5;
  int mt = rest & 3;
  int t = rest >> 2;
  int n32 = lane & 31, q = lane >> 5;
  const float* src = x + ((size_t)t * NB + mt * 32 + n32) * NI + xt * 16 + q * 8;
  _Float16* dst = xpk + (size_t)idx * 8;
  #pragma unroll
  for (int e = 0; e < 8; e++) dst[e] = (_Float16)src[e];
}

__global__ void zero_h(unsigned* __restrict__ hb0, unsigned* __restrict__ bar) {
  int i = blockIdx.x * 256 + threadIdx.x;
  // system-scope stores: initial state must be visible to CP-bypass reads
  if (i < 65536)
    __hip_atomic_store(&hb0[i], 0u, __ATOMIC_RELAXED, __HIP_MEMORY_SCOPE_SYSTEM);
  if (i < 2048)
    __hip_atomic_store(&bar[i], 0u, __ATOMIC_RELAXED, __HIP_MEMORY_SCOPE_SYSTEM);
}

__global__ void __launch_bounds__(256, 1)
lstm_main(const float* __restrict__ x,
          const float* __restrict__ bfv, const float* __restrict__ biv,
          const float* __restrict__ bcv, const float* __restrict__ bov,
          const _Float16* __restrict__ wpack, const _Float16* __restrict__ xpk,
          int xp_en,
          _Float16* __restrict__ hb0, _Float16* __restrict__ hb1,
          unsigned* __restrict__ bar, float* __restrict__ out) {
  extern __shared__ char lds[];
  short* wlds = (short*)lds;                      // [96][64][8] fp16 bits
  float* pbuf = (float*)(lds + LDS_PBUF);         // [(kq*2+mt)*32+n][36]
  float* hshare = (float*)(lds + LDS_HSH);        // [64][10]

  const int tid = threadIdx.x;
  const int lane = tid & 63;
  const int wv = tid >> 6;                        // kq 0..3
  const int hs = blockIdx.x & 127;                // h-slice (8 cols)
  const int mh = blockIdx.x >> 7;                 // batch half

  // ---- load this WG's weight slice into LDS (persistent) ----
  {
    const uint4* src = (const uint4*)wpack + (size_t)hs * 6144;   // 96*64*16B
    uint4* dst = (uint4*)wlds;
    #pragma unroll
    for (int i = 0; i < 24; i++) dst[i * 256 + tid] = src[i * 256 + tid];
  }

  // ---- reducer thread state (tid < 128): 4 cells (m4 block) x 1 h-col ----
  const int rj = tid & 7;
  const int rm4 = tid >> 3;                       // 0..15
  float rbias[4] = {0.f, 0.f, 0.f, 0.f};
  float cstate[4] = {0.f, 0.f, 0.f, 0.f};
  if (tid < 128) {
    int hg = hs * 8 + rj;
    rbias[0] = bfv[hg]; rbias[1] = biv[hg]; rbias[2] = bcv[hg]; rbias[3] = bov[hg];
  }

  const int n32 = lane & 31;
  const int q = lane >> 5;

  // Sharded slot address for THIS WG: 4 slots per 128B line.
  unsigned* myslot = bar + ((blockIdx.x >> 2) * 32 + (blockIdx.x & 3));
  // This WAVE's 32 producers (WGs mh*128 + wv*32 .. +31) occupy 8 sharded lines;
  // lanes 0..7 poll one line each (dwordx4 covers its 4 slots).
  const unsigned* pline = bar + (((mh * 128 + wv * 32) >> 2) + (lane & 7)) * 32;

  __syncthreads();

  for (int t = 0; t < TSTEPS; t++) {
    const _Float16* hrd = (t & 1) ? hb1 : hb0;
    _Float16* hwr = (t & 1) ? hb0 : hb1;

    floatx16 acc0, acc1;
    #pragma unroll
    for (int i = 0; i < 16; i++) { acc0[i] = 0.f; acc1[i] = 0.f; }

    // ---- x-part (kt 64..95): independent of h_{t-1}; overlaps this wave's wait ----
    if (xp_en) {
      // pre-packed fp16 A-frags: pure 16B cached loads, no cvt on critical path
      const _Float16* xp = xpk + (((size_t)t * 4 + mh * 2) * 32) * 64 * 8;
      #pragma unroll
      for (int kk = 0; kk < 8; kk++) {
        int xt = wv * 8 + kk;
        half8 bfrag = *(const half8*)(wlds + ((64 + xt) * 64 + lane) * 8);
        half8 a0 = *(const half8*)(xp + ((size_t)(0 * 32 + xt) * 64 + lane) * 8);
        half8 a1 = *(const half8*)(xp + ((size_t)(1 * 32 + xt) * 64 + lane) * 8);
        acc0 = __builtin_amdgcn_mfma_f32_32x32x16_f16(a0, bfrag, acc0, 0, 0, 0);
        acc1 = __builtin_amdgcn_mfma_f32_32x32x16_f16(a1, bfrag, acc1, 0, 0, 0);
      }
    } else {
      const float* xbase = x + (size_t)t * NB * NI;
      const int r0 = (mh * 2 + 0) * 32 + n32;
      #pragma unroll
      for (int kk = 0; kk < 8; kk++) {
        int xt = wv * 8 + kk;
        half8 bfrag = *(const half8*)(wlds + ((64 + xt) * 64 + lane) * 8);
        const float* xs = xbase + xt * 16 + q * 8;
        float4v xa0 = *(const float4v*)(xs + (size_t)r0 * NI);
        float4v xb0 = *(const float4v*)(xs + (size_t)r0 * NI + 4);
        float4v xa1 = *(const float4v*)(xs + (size_t)(r0 + 32) * NI);
        float4v xb1 = *(const float4v*)(xs + (size_t)(r0 + 32) * NI + 4);
        acc0 = __builtin_amdgcn_mfma_f32_32x32x16_f16(pack8(xa0, xb0), bfrag, acc0, 0, 0, 0);
        acc1 = __builtin_amdgcn_mfma_f32_32x32x16_f16(pack8(xa1, xb1), bfrag, acc1, 0, 0, 0);
      }
    }

    // ---- PER-WAVE dataflow wait: only this wave's 32 producers (8 lines).
    //      No acquire-inv anywhere (h is read via CP-bypass loads below); no
    //      WG-wide gate. The poll's vmcnt(0) drains the wave's counter, keeping
    //      the counted h-load waits below exact.
    if (t > 0) {
      const unsigned need = (unsigned)t;
      for (;;) {
        int ok = 1;
        if (lane < 8) {
          uint4v v = cp_load4(pline);
          ok = (v[0] >= need) & (v[1] >= need) & (v[2] >= need) & (v[3] >= need);
        }
        if (__all(ok)) break;
        __builtin_amdgcn_s_sleep(1);
      }
    }

    // ---- h-part (kt 0..63): 16 tiles per wave, WG-contiguous block layout,
    //      read DIRECTLY from the coherence point. dwordx4 bypass loads (16B/lane:
    //      a0 at base, a1 at base+512 via imm offset). Hand-pipelined: issue 16
    //      loads, then counted vmcnt + sched_barrier per tile (rule #18).
    {
      const char* hp = (const char*)hrd + ((size_t)mh << 17);   // my half: 128 KB
      #pragma unroll
      for (int ph = 0; ph < 2; ph++) {
        uint4v wa[8], wb[8];
        #pragma unroll
        for (int kk = 0; kk < 8; kk++) {
          int ht = wv * 16 + ph * 8 + kk;
          const char* base = hp + (((ht * 2 + q) << 10) | (n32 << 4));
          asm volatile("global_load_dwordx4 %0, %1, off sc0 sc1"
                       : "=v"(wa[kk]) : "v"(base));
          asm volatile("global_load_dwordx4 %0, %1, off offset:512 sc0 sc1"
                       : "=v"(wb[kk]) : "v"(base));
        }
        #pragma unroll
        for (int kk = 0; kk < 8; kk++) {
          int ht = wv * 16 + ph * 8 + kk;
          half8 bfrag = *(const half8*)(wlds + (ht * 64 + lane) * 8);
          asm volatile("s_waitcnt vmcnt(%0)" :: "i"(14 - 2 * kk) : "memory");
          __builtin_amdgcn_sched_barrier(0);
          union { uint4v u; half8 h; } ua, ub;
          ua.u = wa[kk]; ub.u = wb[kk];
          acc0 = __builtin_amdgcn_mfma_f32_32x32x16_f16(ua.h, bfrag, acc0, 0, 0, 0);
          acc1 = __builtin_amdgcn_mfma_f32_32x32x16_f16(ub.h, bfrag, acc1, 0, 0, 0);
        }
      }
    }

    // ---- partials to LDS: D[m][n], m = (r&3) + 8*(r>>2) + 4*q, n = lane&31 ----
    {
      float* b0 = pbuf + ((wv * 2 + 0) * 32 + n32) * 36 + q * 4;
      float* b1 = pbuf + ((wv * 2 + 1) * 32 + n32) * 36 + q * 4;
      #pragma unroll
      for (int rg = 0; rg < 4; rg++) {
        float4v v0 = {acc0[rg * 4 + 0], acc0[rg * 4 + 1], acc0[rg * 4 + 2], acc0[rg * 4 + 3]};
        float4v v1 = {acc1[rg * 4 + 0], acc1[rg * 4 + 1], acc1[rg * 4 + 2], acc1[rg * 4 + 3]};
        *(float4v*)(b0 + rg * 8) = v0;
        *(float4v*)(b1 + rg * 8) = v1;
      }
    }
    __syncthreads();                              // re-converge all waves

    // ---- reduce over kq, gate math, c update (tid < 128) ----
    if (tid < 128) {
      const int mt = rm4 >> 3;
      const int mb = (rm4 & 7) * 4;
      float4v s[4];
      #pragma unroll
      for (int g = 0; g < 4; g++) {
        const float* p = pbuf + (mt * 32 + rj * 4 + g) * 36 + mb;
        float4v a = *(const float4v*)(p);
        a += *(const float4v*)(p + 1 * 2 * 32 * 36);
        a += *(const float4v*)(p + 2 * 2 * 32 * 36);
        a += *(const float4v*)(p + 3 * 2 * 32 * 36);
        s[g] = a;
      }
      #pragma unroll
      for (int r = 0; r < 4; r++) {
        float fg = sigf(s[0][r] + rbias[0]);
        float ig = sigf(s[1][r] + rbias[1]);
        float cg = tanhf(s[2][r] + rbias[2]);
        float og = sigf(s[3][r] + rbias[3]);
        float cn = fg * cstate[r] + ig * cg;
        cstate[r] = cn;
        hshare[(rm4 * 4 + r) * 10 + rj] = og * tanhf(cn);
      }
    }
    __syncthreads();

    // ---- store: h block (coalesced 1KB/WG write-through) + out (plain cached) ----
    {
      const int ml = tid >> 2;
      const int j0 = (tid & 3) * 2;
      float h0 = hshare[ml * 10 + j0];
      float h1 = hshare[ml * 10 + j0 + 1];

      unsigned u = ((unsigned)(unsigned short)f2h(h1) << 16) | (unsigned)(unsigned short)f2h(h0);
      // elem (ml, j0) byte-offset within block = ml*16 + j0*2 = tid*4 exactly.
      unsigned* dst = (unsigned*)((char*)hwr + (((mh * 128 + hs) << 10))) + tid;
      cp_store(dst, u);                            // coalesced write-through

      const int mg = mh * 64 + ml;
      const int hg = hs * 8 + j0;
      *(float2*)(out + ((size_t)t * NB + mg) * HID + hg) = make_float2(h0, h1);
    }

    // ---- arrive: barrier's implicit vmcnt(0) drains every wave's h stores ----
    if (t < TSTEPS - 1) {
      __syncthreads();
      if (tid == 0) cp_store(myslot, (unsigned)(t + 1));
    }
  }
}

extern "C" void kernel_launch(void* const* d_in, const int* in_sizes, int n_in,
                              void* d_out, int out_size, void* d_ws, size_t ws_size,
                              hipStream_t stream) {
  const float* x   = (const float*)d_in[0];
  const float* Wf  = (const float*)d_in[1];
  const float* bf_ = (const float*)d_in[2];
  const float* Wi  = (const float*)d_in[3];
  const float* bi_ = (const float*)d_in[4];
  const float* Wc  = (const float*)d_in[5];
  const float* bc_ = (const float*)d_in[6];
  const float* Wo  = (const float*)d_in[7];
  const float* bo_ = (const float*)d_in[8];
  float* out = (float*)d_out;

  char* ws = (char*)d_ws;
  _Float16* wpack = (_Float16*)(ws + WPACK_OFF);
  _Float16* hb0   = (_Float16*)(ws + HB0_OFF);
  _Float16* hb1   = (_Float16*)(ws + HB1_OFF);
  unsigned* bar   = (unsigned*)(ws + BAR_OFF);
  _Float16* xpk   = (_Float16*)(ws + XPK_OFF);
  int xp_en = (ws_size >= XPK_NEED) ? 1 : 0;

  pack_w<<<3072, 256, 0, stream>>>(Wf, Wi, Wc, Wo, wpack);
  if (xp_en) pack_x<<<16384, 256, 0, stream>>>(x, xpk);
  zero_h<<<257, 256, 0, stream>>>((unsigned*)hb0, bar);

  hipFuncSetAttribute(reinterpret_cast<const void*>(lstm_main),
                      hipFuncAttributeMaxDynamicSharedMemorySize, LDS_TOTAL);

  void* args[] = {(void*)&x, (void*)&bf_, (void*)&bi_, (void*)&bc_, (void*)&bo_,
                  (void*)&wpack, (void*)&xpk, (void*)&xp_en,
                  (void*)&hb0, (void*)&hb1, (void*)&bar, (void*)&out};
  hipLaunchCooperativeKernel(reinterpret_cast<void*>(lstm_main),
                             dim3(NWGS), dim3(256), args, LDS_TOTAL, stream);
}

// Round 17
// 4090.061 us; speedup vs baseline: 1.1518x; 1.1285x over previous
//
#include <hip/hip_runtime.h>
#include <hip/hip_fp16.h>

#define TSTEPS 512
#define NB 128
#define NI 512
#define HID 1024
#define NWGS 256

typedef _Float16 __attribute__((ext_vector_type(8))) half8;
typedef float __attribute__((ext_vector_type(16))) floatx16;
typedef float __attribute__((ext_vector_type(4))) float4v;
typedef unsigned __attribute__((ext_vector_type(4))) uint4v;

// ---------------- ws layout ----------------
// wpack : [hs=128][kt=96][lane=64][e=8] fp16   = 12,582,912 B  (B-frag packed, n=4*j+g)
// hbuf0 : [mh=2][hs=128][tid=256] u32          =    262,144 B  (WG-contiguous h blocks, ping)
// hbuf1 : same                                                 (pong)
// bar   : SHARDED epoch slots: slot(wg) = bar[(wg>>2)*32 + (wg&3)] -- 4 slots per
//         128B line, 64 lines. A wave's 32 producers live on exactly 8 lines.
#define WPACK_OFF 0
#define HB0_OFF   12582912
#define HB1_OFF   12845056
#define BAR_OFF   13107200

// LDS: wlds 98304 B  |  pbuf [kq*2+mt][n=32][36f] 36864 B  |  hshare [64][10f] 2560 B
#define LDS_PBUF  98304
#define LDS_HSH   135168
#define LDS_TOTAL 137728

__device__ __forceinline__ short f2h(float f) {
  _Float16 h = (_Float16)f;
  return *reinterpret_cast<short*>(&h);
}

__device__ __forceinline__ half8 pack8(float4v a, float4v b) {
  half8 r;
  r[0] = (_Float16)a[0]; r[1] = (_Float16)a[1]; r[2] = (_Float16)a[2]; r[3] = (_Float16)a[3];
  r[4] = (_Float16)b[0]; r[5] = (_Float16)b[1]; r[6] = (_Float16)b[2]; r[7] = (_Float16)b[3];
  return r;
}

__device__ __forceinline__ float sigf(float x) { return 1.f / (1.f + __expf(-x)); }

// Coherence-point (bypass L1+L2) accessors. sc0 sc1 = system-scope: loads read
// fresh from the coherence point (NO buffer_inv), stores write through to it.
__device__ __forceinline__ uint4v cp_load4(const unsigned* p) {
  uint4v v;
  asm volatile("global_load_dwordx4 %0, %1, off sc0 sc1" : "=v"(v) : "v"(p) : "memory");
  asm volatile("s_waitcnt vmcnt(0)" ::: "memory");
  return v;
}
__device__ __forceinline__ void cp_store(unsigned* p, unsigned v) {
  asm volatile("global_store_dword %0, %1, off sc0 sc1" :: "v"(p), "v"(v) : "memory");
}

// Pack 4 gate weight matrices (fp32, each [1024][1536]) into fp16 B-fragments.
// B-frag (32x32x16): lane l holds B[n = l&31][k = (l>>5)*8 + e]; n = 4*j + g (j = h-col within slice).
__global__ void pack_w(const float* __restrict__ Wf, const float* __restrict__ Wi,
                       const float* __restrict__ Wc, const float* __restrict__ Wo,
                       _Float16* __restrict__ wpack) {
  int idx = blockIdx.x * 256 + threadIdx.x;      // one 8-elem lane-chunk each
  if (idx >= 128 * 96 * 64) return;
  int lane = idx & 63;
  int rest = idx >> 6;
  int kt = rest % 96;
  int hs = rest / 96;
  int n = lane & 31, q = lane >> 5;
  int j = n >> 2, g = n & 3;
  int row = hs * 8 + j;
  int k = kt * 16 + q * 8;
  const float* W = (g == 0) ? Wf : (g == 1) ? Wi : (g == 2) ? Wc : Wo;
  const float* src = W + (size_t)row * 1536 + k;
  _Float16* dst = wpack + (size_t)idx * 8;
  #pragma unroll
  for (int e = 0; e < 8; e++) dst[e] = (_Float16)src[e];
}

__global__ void zero_h(unsigned* __restrict__ hb0, unsigned* __restrict__ bar) {
  int i = blockIdx.x * 256 + threadIdx.x;
  // system-scope stores: initial state must be visible to CP-bypass reads
  if (i < 65536)
    __hip_atomic_store(&hb0[i], 0u, __ATOMIC_RELAXED, __HIP_MEMORY_SCOPE_SYSTEM);
  if (i < 2048)
    __hip_atomic_store(&bar[i], 0u, __ATOMIC_RELAXED, __HIP_MEMORY_SCOPE_SYSTEM);
}

__global__ void __launch_bounds__(256, 1)
lstm_main(const float* __restrict__ x,
          const float* __restrict__ bfv, const float* __restrict__ biv,
          const float* __restrict__ bcv, const float* __restrict__ bov,
          const _Float16* __restrict__ wpack,
          _Float16* __restrict__ hb0, _Float16* __restrict__ hb1,
          unsigned* __restrict__ bar, float* __restrict__ out) {
  extern __shared__ char lds[];
  short* wlds = (short*)lds;                      // [96][64][8] fp16 bits
  float* pbuf = (float*)(lds + LDS_PBUF);         // [(kq*2+mt)*32+n][36]
  float* hshare = (float*)(lds + LDS_HSH);        // [64][10]

  const int tid = threadIdx.x;
  const int lane = tid & 63;
  const int wv = tid >> 6;                        // kq 0..3
  const int hs = blockIdx.x & 127;                // h-slice (8 cols)
  const int mh = blockIdx.x >> 7;                 // batch half

  // ---- load this WG's weight slice into LDS (persistent) ----
  {
    const uint4* src = (const uint4*)wpack + (size_t)hs * 6144;   // 96*64*16B
    uint4* dst = (uint4*)wlds;
    #pragma unroll
    for (int i = 0; i < 24; i++) dst[i * 256 + tid] = src[i * 256 + tid];
  }

  // ---- reducer thread state (tid < 128): 4 cells (m4 block) x 1 h-col ----
  const int rj = tid & 7;
  const int rm4 = tid >> 3;                       // 0..15
  float rbias[4] = {0.f, 0.f, 0.f, 0.f};
  float cstate[4] = {0.f, 0.f, 0.f, 0.f};
  if (tid < 128) {
    int hg = hs * 8 + rj;
    rbias[0] = bfv[hg]; rbias[1] = biv[hg]; rbias[2] = bcv[hg]; rbias[3] = bov[hg];
  }

  const int n32 = lane & 31;
  const int q = lane >> 5;

  // Sharded slot address for THIS WG: 4 slots per 128B line.
  unsigned* myslot = bar + ((blockIdx.x >> 2) * 32 + (blockIdx.x & 3));
  // This WAVE's 32 producers (WGs mh*128 + wv*32 .. +31) occupy 8 sharded lines;
  // lanes 0..7 poll one line each (dwordx4 covers its 4 slots).
  const unsigned* pline = bar + (((mh * 128 + wv * 32) >> 2) + (lane & 7)) * 32;

  __syncthreads();

  for (int t = 0; t < TSTEPS; t++) {
    const _Float16* hrd = (t & 1) ? hb1 : hb0;
    _Float16* hwr = (t & 1) ? hb0 : hb1;

    floatx16 acc0, acc1;
    #pragma unroll
    for (int i = 0; i < 16; i++) { acc0[i] = 0.f; acc1[i] = 0.f; }

    // ---- x-part (kt 64..95): independent of h_{t-1}; overlaps this wave's wait ----
    {
      const float* xbase = x + (size_t)t * NB * NI;
      const int r0 = (mh * 2 + 0) * 32 + n32;
      #pragma unroll
      for (int kk = 0; kk < 8; kk++) {
        int xt = wv * 8 + kk;                     // 8 x-tiles per wave
        half8 bfrag = *(const half8*)(wlds + ((64 + xt) * 64 + lane) * 8);
        const float* xs = xbase + xt * 16 + q * 8;
        float4v xa0 = *(const float4v*)(xs + (size_t)r0 * NI);
        float4v xb0 = *(const float4v*)(xs + (size_t)r0 * NI + 4);
        float4v xa1 = *(const float4v*)(xs + (size_t)(r0 + 32) * NI);
        float4v xb1 = *(const float4v*)(xs + (size_t)(r0 + 32) * NI + 4);
        acc0 = __builtin_amdgcn_mfma_f32_32x32x16_f16(pack8(xa0, xb0), bfrag, acc0, 0, 0, 0);
        acc1 = __builtin_amdgcn_mfma_f32_32x32x16_f16(pack8(xa1, xb1), bfrag, acc1, 0, 0, 0);
      }
    }

    // ---- PER-WAVE dataflow wait: only this wave's 32 producers (8 lines).
    //      No acquire-inv anywhere (h is read via CP-bypass loads below); no
    //      WG-wide gate -- the wave proceeds into its h-tiles immediately.
    //      The poll's vmcnt(0) drains the wave's counter, keeping the counted
    //      h-load waits below exact.
    if (t > 0) {
      const unsigned need = (unsigned)t;
      for (;;) {
        int ok = 1;
        if (lane < 8) {
          uint4v v = cp_load4(pline);
          ok = (v[0] >= need) & (v[1] >= need) & (v[2] >= need) & (v[3] >= need);
        }
        if (__all(ok)) break;
        __builtin_amdgcn_s_sleep(1);
      }
    }

    // ---- h-part (kt 0..63): 16 tiles per wave, WG-contiguous block layout,
    //      read DIRECTLY from the coherence point. dwordx4 bypass loads (16B/lane:
    //      a0 at base, a1 at base+512 via imm offset). Hand-pipelined: issue 16
    //      loads, then counted vmcnt + sched_barrier per tile (rule #18).
    {
      const char* hp = (const char*)hrd + ((size_t)mh << 17);   // my half: 128 KB
      #pragma unroll
      for (int ph = 0; ph < 2; ph++) {
        uint4v wa[8], wb[8];
        #pragma unroll
        for (int kk = 0; kk < 8; kk++) {
          int ht = wv * 16 + ph * 8 + kk;
          const char* base = hp + (((ht * 2 + q) << 10) | (n32 << 4));
          asm volatile("global_load_dwordx4 %0, %1, off sc0 sc1"
                       : "=v"(wa[kk]) : "v"(base));
          asm volatile("global_load_dwordx4 %0, %1, off offset:512 sc0 sc1"
                       : "=v"(wb[kk]) : "v"(base));
        }
        #pragma unroll
        for (int kk = 0; kk < 8; kk++) {
          int ht = wv * 16 + ph * 8 + kk;
          half8 bfrag = *(const half8*)(wlds + (ht * 64 + lane) * 8);
          asm volatile("s_waitcnt vmcnt(%0)" :: "i"(14 - 2 * kk) : "memory");
          __builtin_amdgcn_sched_barrier(0);
          union { uint4v u; half8 h; } ua, ub;
          ua.u = wa[kk]; ub.u = wb[kk];
          acc0 = __builtin_amdgcn_mfma_f32_32x32x16_f16(ua.h, bfrag, acc0, 0, 0, 0);
          acc1 = __builtin_amdgcn_mfma_f32_32x32x16_f16(ub.h, bfrag, acc1, 0, 0, 0);
        }
      }
    }

    // ---- partials to LDS: D[m][n], m = (r&3) + 8*(r>>2) + 4*q, n = lane&31 ----
    {
      float* b0 = pbuf + ((wv * 2 + 0) * 32 + n32) * 36 + q * 4;
      float* b1 = pbuf + ((wv * 2 + 1) * 32 + n32) * 36 + q * 4;
      #pragma unroll
      for (int rg = 0; rg < 4; rg++) {
        float4v v0 = {acc0[rg * 4 + 0], acc0[rg * 4 + 1], acc0[rg * 4 + 2], acc0[rg * 4 + 3]};
        float4v v1 = {acc1[rg * 4 + 0], acc1[rg * 4 + 1], acc1[rg * 4 + 2], acc1[rg * 4 + 3]};
        *(float4v*)(b0 + rg * 8) = v0;
        *(float4v*)(b1 + rg * 8) = v1;
      }
    }
    __syncthreads();                              // re-converge all waves

    // ---- reduce over kq, gate math, c update (tid < 128) ----
    if (tid < 128) {
      const int mt = rm4 >> 3;
      const int mb = (rm4 & 7) * 4;
      float4v s[4];
      #pragma unroll
      for (int g = 0; g < 4; g++) {
        const float* p = pbuf + (mt * 32 + rj * 4 + g) * 36 + mb;
        float4v a = *(const float4v*)(p);
        a += *(const float4v*)(p + 1 * 2 * 32 * 36);
        a += *(const float4v*)(p + 2 * 2 * 32 * 36);
        a += *(const float4v*)(p + 3 * 2 * 32 * 36);
        s[g] = a;
      }
      #pragma unroll
      for (int r = 0; r < 4; r++) {
        float fg = sigf(s[0][r] + rbias[0]);
        float ig = sigf(s[1][r] + rbias[1]);
        float cg = tanhf(s[2][r] + rbias[2]);
        float og = sigf(s[3][r] + rbias[3]);
        float cn = fg * cstate[r] + ig * cg;
        cstate[r] = cn;
        hshare[(rm4 * 4 + r) * 10 + rj] = og * tanhf(cn);
      }
    }
    __syncthreads();

    // ---- store: h block (coalesced 1KB/WG write-through) + out (plain cached) ----
    {
      const int ml = tid >> 2;
      const int j0 = (tid & 3) * 2;
      float h0 = hshare[ml * 10 + j0];
      float h1 = hshare[ml * 10 + j0 + 1];

      unsigned u = ((unsigned)(unsigned short)f2h(h1) << 16) | (unsigned)(unsigned short)f2h(h0);
      // elem (ml, j0) byte-offset within block = ml*16 + j0*2 = tid*4 exactly.
      unsigned* dst = (unsigned*)((char*)hwr + (((mh * 128 + hs) << 10))) + tid;
      cp_store(dst, u);                            // coalesced write-through

      const int mg = mh * 64 + ml;
      const int hg = hs * 8 + j0;
      *(float2*)(out + ((size_t)t * NB + mg) * HID + hg) = make_float2(h0, h1);
    }

    // ---- arrive: barrier's implicit vmcnt(0) drains every wave's h stores ----
    if (t < TSTEPS - 1) {
      __syncthreads();
      if (tid == 0) cp_store(myslot, (unsigned)(t + 1));
    }
  }
}

extern "C" void kernel_launch(void* const* d_in, const int* in_sizes, int n_in,
                              void* d_out, int out_size, void* d_ws, size_t ws_size,
                              hipStream_t stream) {
  const float* x   = (const float*)d_in[0];
  const float* Wf  = (const float*)d_in[1];
  const float* bf_ = (const float*)d_in[2];
  const float* Wi  = (const float*)d_in[3];
  const float* bi_ = (const float*)d_in[4];
  const float* Wc  = (const float*)d_in[5];
  const float* bc_ = (const float*)d_in[6];
  const float* Wo  = (const float*)d_in[7];
  const float* bo_ = (const float*)d_in[8];
  float* out = (float*)d_out;

  char* ws = (char*)d_ws;
  _Float16* wpack = (_Float16*)(ws + WPACK_OFF);
  _Float16* hb0   = (_Float16*)(ws + HB0_OFF);
  _Float16* hb1   = (_Float16*)(ws + HB1_OFF);
  unsigned* bar   = (unsigned*)(ws + BAR_OFF);

  pack_w<<<3072, 256, 0, stream>>>(Wf, Wi, Wc, Wo, wpack);
  zero_h<<<257, 256, 0, stream>>>((unsigned*)hb0, bar);

  hipFuncSetAttribute(reinterpret_cast<const void*>(lstm_main),
                      hipFuncAttributeMaxDynamicSharedMemorySize, LDS_TOTAL);

  void* args[] = {(void*)&x, (void*)&bf_, (void*)&bi_, (void*)&bc_, (void*)&bo_,
                  (void*)&wpack, (void*)&hb0, (void*)&hb1, (void*)&bar, (void*)&out};
  hipLaunchCooperativeKernel(reinterpret_cast<void*>(lstm_main),
                             dim3(NWGS), dim3(256), args, LDS_TOTAL, stream);
}